// Round 12
// baseline (140.067 us; speedup 1.0000x reference)
//
#include <hip/hip_runtime.h>
#include <math.h>

// Problem dims (from reference): B=4, C=64, T=16, H=128, W=128, fp32.
#define BB 4
#define CC 64
#define TT 16
#define HH 128
#define WW 128
#define HW (HH*WW)

typedef float f32x4 __attribute__((ext_vector_type(4)));

__device__ __forceinline__ float softplus_f(float x) {
    return (x > 20.0f) ? x : log1pf(expf(x));
}

__device__ __forceinline__ float4 splat4(float v) { return make_float4(v, v, v, v); }

// float4 cross-lane fetch within a 32-lane row segment (ds_bpermute x4).
// Out-of-range src wraps (&31) -> caller masks those lanes with a select.
__device__ __forceinline__ float4 shfl4(float4 v, int src) {
    float4 r;
    r.x = __shfl(v.x, src, 32);
    r.y = __shfl(v.y, src, 32);
    r.z = __shfl(v.z, src, 32);
    r.w = __shfl(v.w, src, 32);
    return r;
}

// Pure cache-tap stencil (round-11 structure, 101us) with 2x the thread-
// level parallelism: 2048 blocks x 256 threads, thread owns TWO stacked
// rows. Round 11 was latency-bound (VALUBusy 18%, 16 waves/CU resident,
// grid-capped at 4 blocks/CU); halving per-thread state (~48 -> ~24 data
// regs) lets 8 blocks/CU co-reside (VGPR-capped ~7-8 waves/SIMD) -> 2x
// waves to hide L1/L2 tap latency. Read traffic +20% (6 vs 5 loads/row)
// stays in-cache; HBM unchanged.
//  - NO LDS buffers, NO barriers: waves free-run (every LDS-lockstep
//    variant plateaued >= 121us)
//  - horizontal taps via lane shuffles (round 11: 113 -> 101us win)
//  - block (sh 0..7, bc) owns rows [16sh, 16sh+16) of stack bc for all t;
//    bid%8 == bc%8 keeps all 8 bands of a stack on one XCD
//  - temporal history (t-1, t-2) in registers -> temporal taps free
//  - plain __launch_bounds__(256): ",N" variants pinned VGPR and spilled
//    (rounds 6/8/9)
__global__ __launch_bounds__(256) void lap_st_kernel(
    const float* __restrict__ u,
    const float* __restrict__ Ds,   // (3, 64)
    const float* __restrict__ Dt,   // (2, 64)
    float* __restrict__ out)
{
    const int bid  = blockIdx.x;
    const int sh   = bid >> 8;             // 0..7 : row band
    const int bc   = bid & 255;            // b*C + c
    const int c    = bc & (CC - 1);
    const int tid  = threadIdx.x;
    const int jj   = tid >> 5;             // 0..7 : row pair within band
    const int colc = tid & 31;             // chunk column (lane in row segment)
    const int col  = colc << 2;
    const int r0   = (sh << 4) + (jj << 1); // first of 2 owned rows, 0..126

    const float cs0 = softplus_f(Ds[0 * CC + c]);
    const float cs1 = softplus_f(Ds[1 * CC + c]);
    const float cs2 = softplus_f(Ds[2 * CC + c]);
    const float ct0 = softplus_f(Dt[0 * CC + c]);
    const float ct1 = softplus_f(Dt[1 * CC + c]);
    const float cu = -4.0f * (cs0 + cs1 + cs2) - (ct0 + ct1);

    const size_t bc_off = (size_t)bc * TT * HW;

    float4 pm1[2], pm2[2];

    #pragma unroll 1
    for (int t = 0; t < TT; ++t) {
        const float* __restrict__ up = u + bc_off + (size_t)t * HW;
        f32x4* outp = (f32x4*)(out + bc_off + (size_t)t * HW);

        // center rows (registers; feed +-1 taps, horizontals via shuffle,
        // and the temporal rotate)
        float4 c0[2];
        #pragma unroll
        for (int q = 0; q < 2; ++q)
            c0[q] = *(const float4*)(up + (r0 + q) * WW + col);

        if (t == 0) {   // causal clamp: u[-1] = u[-2] = u[0]
            #pragma unroll
            for (int q = 0; q < 2; ++q) { pm1[q] = c0[q]; pm2[q] = c0[q]; }
        }

        // boundary rows for +-1 taps at the pair edges
        const int rm1 = (r0 - 1 < 0) ? 0 : r0 - 1;
        const int rp2 = (r0 + 2 > HH - 1) ? HH - 1 : r0 + 2;
        const float4 vm1 = *(const float4*)(up + rm1 * WW + col);
        const float4 vp2 = *(const float4*)(up + rp2 * WW + col);

        #pragma unroll
        for (int q = 0; q < 2; ++q) {
            const int r = r0 + q;

            // ---- vertical taps (d=1 from registers; d=4,16 clamped loads) ----
            const float4 vu1 = (q == 0) ? vm1 : c0[0];
            const float4 vd1 = (q == 1) ? vp2 : c0[1];
            int ru4 = r - 4;  ru4 = ru4 < 0 ? 0 : ru4;
            int rd4 = r + 4;  rd4 = rd4 > HH - 1 ? HH - 1 : rd4;
            int ru16 = r - 16; ru16 = ru16 < 0 ? 0 : ru16;
            int rd16 = r + 16; rd16 = rd16 > HH - 1 ? HH - 1 : rd16;
            const float4 vu4  = *(const float4*)(up + ru4  * WW + col);
            const float4 vd4  = *(const float4*)(up + rd4  * WW + col);
            const float4 vu16 = *(const float4*)(up + ru16 * WW + col);
            const float4 vd16 = *(const float4*)(up + rd16 * WW + col);

            const float4 cc = c0[q];

            // ---- horizontal taps from adjacent lanes' registers ----
            const float4 L4  = shfl4(cc, colc - 1);
            const float4 R4  = shfl4(cc, colc + 1);
            const float4 L16 = shfl4(cc, colc - 4);
            const float4 R16 = shfl4(cc, colc + 4);
            const float e0   = __shfl(cc.x, 0, 32);    // row elem 0
            const float e127 = __shfl(cc.w, 31, 32);   // row elem 127
            const float4 l4  = (colc >= 1)  ? L4  : splat4(e0);
            const float4 r4  = (colc <= 30) ? R4  : splat4(e127);
            const float4 l16 = (colc >= 4)  ? L16 : splat4(e0);
            const float4 r16 = (colc <= 27) ? R16 : splat4(e127);

            const float4 p1 = pm1[q];
            const float4 p2 = pm2[q];

            f32x4 o;
            o.x = cs0 * (vu1.x + vd1.x + l4.w + cc.y)
                + cs1 * (vu4.x + vd4.x + l4.x + r4.x)
                + cs2 * (vu16.x + vd16.x + l16.x + r16.x)
                + cu * cc.x + ct0 * p1.x + ct1 * p2.x;
            o.y = cs0 * (vu1.y + vd1.y + cc.x + cc.z)
                + cs1 * (vu4.y + vd4.y + l4.y + r4.y)
                + cs2 * (vu16.y + vd16.y + l16.y + r16.y)
                + cu * cc.y + ct0 * p1.y + ct1 * p2.y;
            o.z = cs0 * (vu1.z + vd1.z + cc.y + cc.w)
                + cs1 * (vu4.z + vd4.z + l4.z + r4.z)
                + cs2 * (vu16.z + vd16.z + l16.z + r16.z)
                + cu * cc.z + ct0 * p1.z + ct1 * p2.z;
            o.w = cs0 * (vu1.w + vd1.w + cc.z + r4.x)
                + cs1 * (vu4.w + vd4.w + l4.w + r4.w)
                + cs2 * (vu16.w + vd16.w + l16.w + r16.w)
                + cu * cc.w + ct0 * p1.w + ct1 * p2.w;

            __builtin_nontemporal_store(o, &outp[r * 32 + colc]);
        }

        // rotate temporal history
        #pragma unroll
        for (int q = 0; q < 2; ++q) { pm2[q] = pm1[q]; pm1[q] = c0[q]; }
    }
}

extern "C" void kernel_launch(void* const* d_in, const int* in_sizes, int n_in,
                              void* d_out, int out_size, void* d_ws, size_t ws_size,
                              hipStream_t stream) {
    const float* u  = (const float*)d_in[0];
    const float* Ds = (const float*)d_in[1];
    const float* Dt = (const float*)d_in[2];
    float* out = (float*)d_out;

    const int nblocks = 8 * BB * CC;   // 2048 blocks -> up to 8 per CU
    lap_st_kernel<<<dim3(nblocks), dim3(256), 0, stream>>>(u, Ds, Dt, out);
}

// Round 13
// 113.107 us; speedup vs baseline: 1.2384x; 1.2384x over previous
//
#include <hip/hip_runtime.h>
#include <math.h>

// Problem dims (from reference): B=4, C=64, T=16, H=128, W=128, fp32.
#define BB 4
#define CC 64
#define TT 16
#define HH 128
#define WW 128
#define HW (HH*WW)

typedef float f32x4 __attribute__((ext_vector_type(4)));

__device__ __forceinline__ float softplus_f(float x) {
    return (x > 20.0f) ? x : log1pf(expf(x));
}

__device__ __forceinline__ float4 splat4(float v) { return make_float4(v, v, v, v); }

// float4 cross-lane fetch within a 32-lane row segment (ds_bpermute x4).
__device__ __forceinline__ float4 shfl4(float4 v, int src) {
    float4 r;
    r.x = __shfl(v.x, src, 32);
    r.y = __shfl(v.y, src, 32);
    r.z = __shfl(v.z, src, 32);
    r.w = __shfl(v.w, src, 32);
    return r;
}

// Round-11 structure (101us best: 1024 blocks x 256 thr, 4-row threads,
// shuffle horizontals, no LDS, no barriers) + CROSS-PLANE PREFETCH:
// plane t+1's center+boundary rows (6 loads/thread) are issued BEFORE the
// compute of plane t, so each wave keeps next-plane HBM loads in flight
// under its VALU phase. No barriers -> nothing drains vmcnt; the waits
// land at the rotate after compute (round-4/8 sink pathology was
// barrier-driven). Round-12 lesson: MORE BLOCKS thrash L3 (2048 blocks:
// FETCH 164->326 MB, 140us) -> keep 4 blocks/CU and add ILP instead.
//  - block (sh 0..3, bc) owns rows [32sh,32sh+32) of stack bc for all t;
//    bid%8 == bc%8 keeps a stack's bands on one XCD
//  - thread owns 4 stacked rows: d=1 vertical taps from own registers
//  - temporal history (t-1, t-2) in registers -> temporal taps free
//  - plain __launch_bounds__(256): ",N" variants pinned VGPR=64 and
//    spilled (rounds 6/8/9)
__global__ __launch_bounds__(256) void lap_st_kernel(
    const float* __restrict__ u,
    const float* __restrict__ Ds,   // (3, 64)
    const float* __restrict__ Dt,   // (2, 64)
    float* __restrict__ out)
{
    const int bid  = blockIdx.x;
    const int sh   = bid >> 8;             // 0..3 : row band
    const int bc   = bid & 255;            // b*C + c
    const int c    = bc & (CC - 1);
    const int tid  = threadIdx.x;
    const int jj   = tid >> 5;             // 0..7 : row group within band
    const int colc = tid & 31;             // chunk column (lane in row segment)
    const int col  = colc << 2;
    const int r0   = (sh << 5) + (jj << 2); // first of 4 owned rows, 0..124

    const float cs0 = softplus_f(Ds[0 * CC + c]);
    const float cs1 = softplus_f(Ds[1 * CC + c]);
    const float cs2 = softplus_f(Ds[2 * CC + c]);
    const float ct0 = softplus_f(Dt[0 * CC + c]);
    const float ct1 = softplus_f(Dt[1 * CC + c]);
    const float cu = -4.0f * (cs0 + cs1 + cs2) - (ct0 + ct1);

    const size_t bc_off = (size_t)bc * TT * HW;
    const int rm1 = (r0 - 1 < 0) ? 0 : r0 - 1;         // fixed row indices
    const int rp4 = (r0 + 4 > HH - 1) ? HH - 1 : r0 + 4;

    float4 pm1[4], pm2[4];
    float4 c0[4], vm1, vp4;          // current plane center + boundary
    float4 nc0[4], nvm1, nvp4;       // prefetched next plane

    // ---- prologue: load plane 0 center+boundary directly ----
    {
        const float* up = u + bc_off;
        #pragma unroll
        for (int q = 0; q < 4; ++q)
            c0[q] = *(const float4*)(up + (r0 + q) * WW + col);
        vm1 = *(const float4*)(up + rm1 * WW + col);
        vp4 = *(const float4*)(up + rp4 * WW + col);
        #pragma unroll
        for (int q = 0; q < 4; ++q) { pm1[q] = c0[q]; pm2[q] = c0[q]; }
    }

    #pragma unroll 1
    for (int t = 0; t < TT; ++t) {
        const float* __restrict__ up = u + bc_off + (size_t)t * HW;
        f32x4* outp = (f32x4*)(out + bc_off + (size_t)t * HW);

        // ---- prefetch plane t+1 center+boundary (in flight during compute) ----
        if (t < TT - 1) {
            const float* un = up + HW;
            #pragma unroll
            for (int q = 0; q < 4; ++q)
                nc0[q] = *(const float4*)(un + (r0 + q) * WW + col);
            nvm1 = *(const float4*)(un + rm1 * WW + col);
            nvp4 = *(const float4*)(un + rp4 * WW + col);
        }

        #pragma unroll
        for (int q = 0; q < 4; ++q) {
            const int r = r0 + q;

            // ---- vertical taps (d=1 from registers; d=4,16 clamped loads) ----
            const float4 vu1 = (q == 0) ? vm1 : c0[q - 1];
            const float4 vd1 = (q == 3) ? vp4 : c0[q + 1];
            float4 vu4, vd4;
            if (q == 3) vu4 = vm1;                       // r-4 == r0-1
            else { int rr = r - 4; rr = rr < 0 ? 0 : rr;
                   vu4 = *(const float4*)(up + rr * WW + col); }
            if (q == 0) vd4 = vp4;                       // r+4 == r0+4
            else { int rr = r + 4; rr = rr > HH - 1 ? HH - 1 : rr;
                   vd4 = *(const float4*)(up + rr * WW + col); }
            int ru16 = r - 16; ru16 = ru16 < 0 ? 0 : ru16;
            int rd16 = r + 16; rd16 = rd16 > HH - 1 ? HH - 1 : rd16;
            const float4 vu16 = *(const float4*)(up + ru16 * WW + col);
            const float4 vd16 = *(const float4*)(up + rd16 * WW + col);

            const float4 cc = c0[q];

            // ---- horizontal taps from adjacent lanes' registers ----
            const float4 L4  = shfl4(cc, colc - 1);
            const float4 R4  = shfl4(cc, colc + 1);
            const float4 L16 = shfl4(cc, colc - 4);
            const float4 R16 = shfl4(cc, colc + 4);
            const float e0   = __shfl(cc.x, 0, 32);    // row elem 0
            const float e127 = __shfl(cc.w, 31, 32);   // row elem 127
            const float4 l4  = (colc >= 1)  ? L4  : splat4(e0);
            const float4 r4  = (colc <= 30) ? R4  : splat4(e127);
            const float4 l16 = (colc >= 4)  ? L16 : splat4(e0);
            const float4 r16 = (colc <= 27) ? R16 : splat4(e127);

            const float4 p1 = pm1[q];
            const float4 p2 = pm2[q];

            f32x4 o;
            o.x = cs0 * (vu1.x + vd1.x + l4.w + cc.y)
                + cs1 * (vu4.x + vd4.x + l4.x + r4.x)
                + cs2 * (vu16.x + vd16.x + l16.x + r16.x)
                + cu * cc.x + ct0 * p1.x + ct1 * p2.x;
            o.y = cs0 * (vu1.y + vd1.y + cc.x + cc.z)
                + cs1 * (vu4.y + vd4.y + l4.y + r4.y)
                + cs2 * (vu16.y + vd16.y + l16.y + r16.y)
                + cu * cc.y + ct0 * p1.y + ct1 * p2.y;
            o.z = cs0 * (vu1.z + vd1.z + cc.y + cc.w)
                + cs1 * (vu4.z + vd4.z + l4.z + r4.z)
                + cs2 * (vu16.z + vd16.z + l16.z + r16.z)
                + cu * cc.z + ct0 * p1.z + ct1 * p2.z;
            o.w = cs0 * (vu1.w + vd1.w + cc.z + r4.x)
                + cs1 * (vu4.w + vd4.w + l4.w + r4.w)
                + cs2 * (vu16.w + vd16.w + l16.w + r16.w)
                + cu * cc.w + ct0 * p1.w + ct1 * p2.w;

            __builtin_nontemporal_store(o, &outp[r * 32 + colc]);
        }

        // rotate: temporal history and prefetched plane (vmcnt waits land here)
        if (t < TT - 1) {
            #pragma unroll
            for (int q = 0; q < 4; ++q) {
                pm2[q] = pm1[q]; pm1[q] = c0[q]; c0[q] = nc0[q];
            }
            vm1 = nvm1; vp4 = nvp4;
        }
    }
}

extern "C" void kernel_launch(void* const* d_in, const int* in_sizes, int n_in,
                              void* d_out, int out_size, void* d_ws, size_t ws_size,
                              hipStream_t stream) {
    const float* u  = (const float*)d_in[0];
    const float* Ds = (const float*)d_in[1];
    const float* Dt = (const float*)d_in[2];
    float* out = (float*)d_out;

    const int nblocks = 4 * BB * CC;   // 1024 blocks = 4 per CU (best locality)
    lap_st_kernel<<<dim3(nblocks), dim3(256), 0, stream>>>(u, Ds, Dt, out);
}